// Round 1
// baseline (962.755 us; speedup 1.0000x reference)
//
#include <hip/hip_runtime.h>

#define B_   32
#define L_   512
#define S1_  513
#define LP_  16
#define NEG  (-1.0e9f)
#define NINF (-3.0e38f)
#define L2E  1.4426950408889634f
#define LN2f 0.6931471805599453f

// ---------------- setup kernels ----------------

// cs[b,c,0]=0; cs[b,c,i+1]=cumsum(log ss3[b,c,:])[i]
__global__ void k_cumsum(const float* __restrict__ ss3, float* __restrict__ cs) {
  int b = blockIdx.x, c = blockIdx.y;
  __shared__ float buf[L_];
  int t = threadIdx.x;                    // 512 threads
  buf[t] = logf(ss3[(b * 3 + c) * L_ + t]);
  __syncthreads();
  for (int d = 1; d < L_; d <<= 1) {
    float add = (t >= d) ? buf[t - d] : 0.0f;
    __syncthreads();
    buf[t] += add;
    __syncthreads();
  }
  float* out = cs + (b * 3 + c) * S1_;
  if (t == 0) out[0] = 0.0f;
  out[t + 1] = buf[t];
}

// QT[c][k][j] = Q[c][j][k];  colmax[c][k] = max_j Q[c][j][k]
__global__ void k_qt(const float* __restrict__ Q, float* __restrict__ QT,
                     float* __restrict__ colmax) {
  int c = blockIdx.y;
  int k = blockIdx.x * 64 + threadIdx.x;
  if (k >= S1_) return;
  const float* q = Q + c * S1_ * S1_;
  float* qt = QT + c * S1_ * S1_ + k * S1_;
  float m = NINF;
  for (int j = 0; j < S1_; ++j) {
    float v = q[j * S1_ + k];
    m = fmaxf(m, v);
    qt[j] = v;
  }
  colmax[c * S1_ + k] = m;
}

// rowmax[c][j] = max_k Q[c][j][k]  (read QT coalesced)
__global__ void k_rowmax(const float* __restrict__ QT, float* __restrict__ rowmax) {
  int c = blockIdx.y;
  int j = blockIdx.x * 64 + threadIdx.x;
  if (j >= S1_) return;
  const float* qt = QT + c * S1_ * S1_;
  float m = NINF;
  for (int k = 0; k < S1_; ++k) m = fmaxf(m, qt[k * S1_ + j]);
  rowmax[c * S1_ + j] = m;
}

// ---------------- main scan kernel ----------------
// grid 64 blocks: blockIdx.x = b*2 + dir (dir 0 = forward alpha, 1 = backward beta)
__global__ __launch_bounds__(512) void k_scan(
    const float* __restrict__ Q, const float* __restrict__ QT,
    const float* __restrict__ cs,
    const float* __restrict__ colmax, const float* __restrict__ rowmax,
    const int* __restrict__ pattern, const int* __restrict__ ls,
    float* __restrict__ a_buf, float* __restrict__ b_buf) {
  const int b   = blockIdx.x >> 1;
  const int dir = blockIdx.x & 1;
  const int tid = threadIdx.x;
  const int lane = tid & 63;
  const int w    = tid >> 6;
  const int tile = (w < 4) ? w : (11 - w);   // SIMD load balance for triangular loops
  const int myk  = tile * 64 + lane;         // 0..511; k=512 handled cooperatively

  __shared__ float cs3[3 * S1_];
  __shared__ float acur[S1_];
  __shared__ float zl[S1_];
  __shared__ float sc[S1_];
  __shared__ float araw[S1_];
  __shared__ float red[8];
  __shared__ float bcast[2];
  __shared__ int   pat[LP_];

  for (int i = tid; i < 3 * S1_; i += 512) cs3[i] = cs[b * 3 * S1_ + i];
  if (tid < LP_) pat[tid] = pattern[tid];
  const int myls = ls[b];

  float* obuf = dir ? b_buf : a_buf;
  {
    const int initk = dir ? myls : 0;
    const int row0  = dir ? LP_ : 0;
    float* orow = obuf + (b * (LP_ + 1) + row0) * S1_;
    for (int i = tid; i < S1_; i += 512) {
      float v = (i == initk) ? 0.0f : NEG;
      acur[i] = v;
      orow[i] = v;
    }
  }
  float n = 0.0f;
  __syncthreads();

  for (int s = 0; s < LP_; ++s) {
    const int c = pat[dir ? (LP_ - 1 - s) : s];
    const float* csr = cs3 + c * S1_;

    // --- A: z vector.  fwd: z[j]=a[j]-cs[j] ;  bwd: z[k]=b[k]+cs[k]
    for (int i = tid; i < S1_; i += 512) {
      float cv = csr[i];
      zl[i] = acur[i] + (dir ? cv : -cv);
    }
    __syncthreads();

    // --- B: inclusive max-scan of zl (fwd) / reversed zl (bwd), Hillis-Steele
    for (int i = tid; i < S1_; i += 512) sc[i] = dir ? zl[S1_ - 1 - i] : zl[i];
    __syncthreads();
    for (int d = 1; d < S1_; d <<= 1) {
      float nv0 = fmaxf(sc[tid], (tid >= d) ? sc[tid - d] : NINF);
      float nv1 = NINF;
      if (tid == 0) nv1 = fmaxf(sc[512], sc[512 - d]);
      __syncthreads();
      sc[tid] = nv0;
      if (tid == 0) sc[512] = nv1;
      __syncthreads();
    }

    // --- C: main triangular LSE pass (single pass, prefix-max shifted)
    if (!dir) {
      const int k = myk;
      if (k == 0) {
        araw[0] = NEG;                               // empty source range
      } else {
        const float msh = sc[k - 1] + colmax[c * S1_ + k];
        const float mB  = -msh * L2E;
        const float* qp = Q + c * S1_ * S1_ + k;
        float s0 = 0.f, s1 = 0.f, s2 = 0.f, s3 = 0.f;
        int j = 0;
        for (; j + 4 <= k; j += 4) {
          float x0 = qp[(j + 0) * S1_] + zl[j + 0];
          float x1 = qp[(j + 1) * S1_] + zl[j + 1];
          float x2 = qp[(j + 2) * S1_] + zl[j + 2];
          float x3 = qp[(j + 3) * S1_] + zl[j + 3];
          s0 += exp2f(fmaf(x0, L2E, mB));
          s1 += exp2f(fmaf(x1, L2E, mB));
          s2 += exp2f(fmaf(x2, L2E, mB));
          s3 += exp2f(fmaf(x3, L2E, mB));
        }
        for (; j < k; ++j)
          s0 += exp2f(fmaf(qp[j * S1_] + zl[j], L2E, mB));
        const float ssum = (s0 + s1) + (s2 + s3);
        araw[k] = csr[k] + msh + log2f(ssum) * LN2f;
      }
      // k = 512 cooperatively (all 512 threads, one j each)
      {
        const float msh = sc[511] + colmax[c * S1_ + 512];
        const float mB  = -msh * L2E;
        float part = exp2f(fmaf(Q[c * S1_ * S1_ + tid * S1_ + 512] + zl[tid], L2E, mB));
        for (int o = 1; o < 64; o <<= 1) part += __shfl_xor(part, o);
        if (lane == 0) red[w] = part;
        __syncthreads();
        if (tid == 0) {
          float t = 0.f;
          for (int i = 0; i < 8; ++i) t += red[i];
          araw[512] = csr[512] + msh + log2f(t) * LN2f;
        }
      }
    } else {
      const int jj = myk;                             // 0..511 ; j=512 -> NEG
      const float msh = sc[511 - jj] + rowmax[c * S1_ + jj];
      const float mB  = -msh * L2E;
      const float* qp = QT + c * S1_ * S1_ + jj;
      float s0 = 0.f, s1 = 0.f, s2 = 0.f, s3 = 0.f;
      int k2 = jj + 1;
      for (; k2 + 4 <= S1_; k2 += 4) {
        float x0 = qp[(k2 + 0) * S1_] + zl[k2 + 0];
        float x1 = qp[(k2 + 1) * S1_] + zl[k2 + 1];
        float x2 = qp[(k2 + 2) * S1_] + zl[k2 + 2];
        float x3 = qp[(k2 + 3) * S1_] + zl[k2 + 3];
        s0 += exp2f(fmaf(x0, L2E, mB));
        s1 += exp2f(fmaf(x1, L2E, mB));
        s2 += exp2f(fmaf(x2, L2E, mB));
        s3 += exp2f(fmaf(x3, L2E, mB));
      }
      for (; k2 < S1_; ++k2)
        s0 += exp2f(fmaf(qp[k2 * S1_] + zl[k2], L2E, mB));
      const float ssum = (s0 + s1) + (s2 + s3);
      araw[jj] = -csr[jj] + msh + log2f(ssum) * LN2f;
      if (tid == 0) araw[512] = NEG;
    }
    __syncthreads();

    // --- D: lse = LSE over araw[0..512]
    float v = araw[tid];
    if (tid == 0) v = fmaxf(v, araw[512]);
    for (int o = 1; o < 64; o <<= 1) v = fmaxf(v, __shfl_xor(v, o));
    if (lane == 0) red[w] = v;
    __syncthreads();
    if (tid == 0) {
      float m = red[0];
      for (int i = 1; i < 8; ++i) m = fmaxf(m, red[i]);
      bcast[0] = m;
    }
    __syncthreads();
    const float amax = bcast[0];
    float e = exp2f((araw[tid] - amax) * L2E);
    if (tid == 0) e += exp2f((araw[512] - amax) * L2E);
    for (int o = 1; o < 64; o <<= 1) e += __shfl_xor(e, o);
    if (lane == 0) red[w] = e;
    __syncthreads();
    if (tid == 0) {
      float t2 = 0.f;
      for (int i = 0; i < 8; ++i) t2 += red[i];
      bcast[1] = amax + log2f(t2) * LN2f;
    }
    __syncthreads();
    const float lse = bcast[1];
    n += lse;

    // --- E: normalize, store row (unnormalized = normalized + n)
    const int row = dir ? (LP_ - 1 - s) : (s + 1);
    float* orow = obuf + (b * (LP_ + 1) + row) * S1_;
    for (int i = tid; i < S1_; i += 512) {
      float an = araw[i] - lse;
      acur[i] = an;
      orow[i] = an + n;
    }
    __syncthreads();
  }
}

// ---------------- epilogue ----------------
__global__ void k_out(const float* __restrict__ a_buf, const float* __restrict__ b_buf,
                      const int* __restrict__ ls, float* __restrict__ out) {
  const int TOT = B_ * (LP_ + 1) * S1_;
  int idx = blockIdx.x * 256 + threadIdx.x;
  if (idx >= TOT) return;
  int b = idx / ((LP_ + 1) * S1_);
  float M = a_buf[(b * (LP_ + 1) + LP_) * S1_ + ls[b]];
  out[idx] = a_buf[idx] + b_buf[idx] - M;
}

// ---------------- launcher ----------------
extern "C" void kernel_launch(void* const* d_in, const int* in_sizes, int n_in,
                              void* d_out, int out_size, void* d_ws, size_t ws_size,
                              hipStream_t stream) {
  const float* ss3     = (const float*)d_in[0];
  const float* Q       = (const float*)d_in[1];
  const int*   pattern = (const int*)d_in[2];
  const int*   ls      = (const int*)d_in[3];
  float* out = (float*)d_out;

  float* ws     = (float*)d_ws;
  float* cs     = ws;                         // B*3*S1 = 49248
  float* QT     = cs + B_ * 3 * S1_;          // 3*S1*S1 = 789507
  float* colmax = QT + 3 * S1_ * S1_;         // 3*S1 = 1539
  float* rowmax = colmax + 3 * S1_;           // 1539
  float* a_buf  = rowmax + 3 * S1_;           // B*(LP+1)*S1 = 279072
  float* b_buf  = a_buf + B_ * (LP_ + 1) * S1_;

  k_cumsum<<<dim3(B_, 3), 512, 0, stream>>>(ss3, cs);
  k_qt    <<<dim3(9, 3), 64, 0, stream>>>(Q, QT, colmax);
  k_rowmax<<<dim3(9, 3), 64, 0, stream>>>(QT, rowmax);
  k_scan  <<<2 * B_, 512, 0, stream>>>(Q, QT, cs, colmax, rowmax, pattern, ls, a_buf, b_buf);

  const int TOT = B_ * (LP_ + 1) * S1_;
  k_out<<<(TOT + 255) / 256, 256, 0, stream>>>(a_buf, b_buf, ls, out);
}

// Round 2
// 600.455 us; speedup vs baseline: 1.6034x; 1.6034x over previous
//
#include <hip/hip_runtime.h>

#define B_   32
#define L_   512
#define S1_  513
#define LP_  16
#define NEG  (-1.0e9f)
#define NINF (-3.0e38f)
#define L2E  1.4426950408889634f
#define LN2f 0.6931471805599453f

typedef unsigned short ushort_t;

__device__ __forceinline__ float bf2f(ushort_t u) {
  return __uint_as_float(((unsigned int)u) << 16);
}
__device__ __forceinline__ ushort_t f2bf(float f) {
  unsigned int u = __float_as_uint(f);
  unsigned int r = (u + 0x7FFFu + ((u >> 16) & 1u)) >> 16;
  return (ushort_t)r;
}

// ---------------- setup kernels ----------------

// cs[b,c,0]=0; cs[b,c,i+1]=cumsum(log ss3[b,c,:])[i]
__global__ void k_cumsum(const float* __restrict__ ss3, float* __restrict__ cs) {
  int b = blockIdx.x, c = blockIdx.y;
  __shared__ float buf[L_];
  int t = threadIdx.x;                    // 512 threads
  buf[t] = logf(ss3[(b * 3 + c) * L_ + t]);
  __syncthreads();
  for (int d = 1; d < L_; d <<= 1) {
    float add = (t >= d) ? buf[t - d] : 0.0f;
    __syncthreads();
    buf[t] += add;
    __syncthreads();
  }
  float* out = cs + (b * 3 + c) * S1_;
  if (t == 0) out[0] = 0.0f;
  out[t + 1] = buf[t];
}

// Ebf[c][j][k] = bf16(exp(Q[c][j][k]));  ETb[c][k][j] = same, transposed.
__global__ void k_prep(const float* __restrict__ Q, ushort_t* __restrict__ Ebf,
                       ushort_t* __restrict__ ETb) {
  __shared__ float tile[32][33];
  const int c = blockIdx.z;
  const int x = blockIdx.x * 32 + threadIdx.x;
  const float* q = Q + c * S1_ * S1_;
  for (int dy = threadIdx.y; dy < 32; dy += 8) {
    int y = blockIdx.y * 32 + dy;
    if (x < S1_ && y < S1_) {
      float e = expf(q[y * S1_ + x]);
      Ebf[c * S1_ * S1_ + y * S1_ + x] = f2bf(e);
      tile[dy][threadIdx.x] = e;
    }
  }
  __syncthreads();
  const int xT = blockIdx.y * 32 + threadIdx.x;
  for (int dy = threadIdx.y; dy < 32; dy += 8) {
    int yT = blockIdx.x * 32 + dy;
    if (xT < S1_ && yT < S1_)
      ETb[c * S1_ * S1_ + yT * S1_ + xT] = f2bf(tile[threadIdx.x][dy]);
  }
}

// ---------------- main scan kernel ----------------
// 64 blocks: blockIdx.x = b*2 + dir (0 = forward alpha, 1 = backward beta)
__global__ __launch_bounds__(512) void k_scan(
    const ushort_t* __restrict__ Ebf, const ushort_t* __restrict__ ETb,
    const float* __restrict__ cs, const int* __restrict__ pattern,
    const int* __restrict__ ls,
    float* __restrict__ a_buf, float* __restrict__ b_buf) {
  const int b   = blockIdx.x >> 1;
  const int dir = blockIdx.x & 1;
  const int tid = threadIdx.x;
  const int lane = tid & 63;
  const int w    = tid >> 6;
  const int tile = (w < 4) ? w : (11 - w);   // SIMD pairing (w, w+4) -> tiles sum to 7
  const int myk  = tile * 64 + lane;         // 0..511 (permutation)

  __shared__ float cs3[3 * S1_];
  __shared__ float zl[S1_];                  // z values, idx 0..511 used
  __shared__ float wexp[512];                // exp(z - tilemax)
  __shared__ float tmaxs[9];                 // per-tile max; [8] = zl[512] (bwd)
  __shared__ float red[8];
  __shared__ int   pat[LP_];

  for (int i = tid; i < 3 * S1_; i += 512) cs3[i] = cs[b * 3 * S1_ + i];
  if (tid < LP_) pat[tid] = pattern[tid];
  const int myls = ls[b];

  float* obuf = dir ? b_buf : a_buf;
  float areg, areg512;
  {
    const int initk = dir ? myls : 0;
    areg    = (myk == initk) ? 0.0f : NEG;
    areg512 = (dir && myls == 512) ? 0.0f : NEG;
    const int row0 = dir ? LP_ : 0;
    float* orow = obuf + (b * (LP_ + 1) + row0) * S1_;
    orow[myk] = areg;
    if (tid == 0) orow[512] = areg512;
  }
  __syncthreads();

  for (int s = 0; s < LP_; ++s) {
    const int c = pat[dir ? (LP_ - 1 - s) : s];
    const float* csr = cs3 + c * S1_;
    const float mycs = csr[myk];

    // --- phase 1: z.  fwd: z[j]=a[j]-cs[j] ; bwd: z[k]=b[k]+cs[k]
    const float z = areg + (dir ? mycs : -mycs);
    zl[myk] = z;
    float z512 = 0.0f;
    if (dir && tid == 0) z512 = areg512 + csr[512];

    // --- phase 2: per-wave (= per-tile) inclusive max scan + tile max
    float pfx = z;
    float tmax;
    if (!dir) {
      #pragma unroll
      for (int d = 1; d < 64; d <<= 1) {
        float o = __shfl_up(pfx, d);
        if (lane >= d) pfx = fmaxf(pfx, o);
      }
      tmax = __shfl(pfx, 63);
      if (lane == 63) tmaxs[tile] = pfx;
    } else {
      #pragma unroll
      for (int d = 1; d < 64; d <<= 1) {
        float o = __shfl_down(pfx, d);
        if (lane < 64 - d) pfx = fmaxf(pfx, o);
      }
      tmax = __shfl(pfx, 0);
      if (lane == 0) tmaxs[tile] = pfx;
      if (tid == 0) tmaxs[8] = z512;
    }
    __syncthreads();                               // barrier A

    // --- phase 3: cross-tile offset, per-k shift msh, wexp
    float msh;
    if (!dir) {
      float off = NINF;
      for (int t2 = 0; t2 < tile; ++t2) off = fmaxf(off, tmaxs[t2]);
      float p1 = __shfl_up(pfx, 1);
      msh = fmaxf((lane == 0) ? NINF : p1, off);   // prefix max over j<k
    } else {
      float off = tmaxs[8];                        // zl[512]
      for (int t2 = tile + 1; t2 < 8; ++t2) off = fmaxf(off, tmaxs[t2]);
      float p1 = __shfl_down(pfx, 1);
      msh = fmaxf((lane == 63) ? NINF : p1, off);  // suffix max over k>jj
    }
    wexp[myk] = exp2f((z - tmax) * L2E);
    __syncthreads();                               // barrier B

    // --- phase 4: triangular weighted sum (pure FMA on full tiles)
    float acc = 0.0f;
    if (!dir) {
      const ushort_t* ecol = Ebf + c * S1_ * S1_ + myk;
      for (int t = 0; t < tile; ++t) {             // wave-uniform bound
        const ushort_t* ep = ecol + t * 64 * S1_;
        const float4* wv = (const float4*)(wexp + t * 64);
        float s0 = 0.f, s1 = 0.f, s2 = 0.f, s3 = 0.f;
        #pragma unroll
        for (int q = 0; q < 16; ++q) {
          float4 w4 = wv[q];
          s0 += bf2f(ep[(q * 4 + 0) * S1_]) * w4.x;
          s1 += bf2f(ep[(q * 4 + 1) * S1_]) * w4.y;
          s2 += bf2f(ep[(q * 4 + 2) * S1_]) * w4.z;
          s3 += bf2f(ep[(q * 4 + 3) * S1_]) * w4.w;
        }
        acc += exp2f((tmaxs[t] - msh) * L2E) * ((s0 + s1) + (s2 + s3));
      }
      { // boundary tile: j = tile*64 .. myk-1  (count = lane)
        const ushort_t* ep = ecol + tile * 64 * S1_;
        const float* zp = zl + tile * 64;
        for (int q = 0; q < lane; ++q)
          acc += bf2f(ep[q * S1_]) * exp2f((zp[q] - msh) * L2E);
      }
      float ar = (acc > 0.0f) ? (csr[myk] + msh + log2f(acc) * LN2f) : NEG;

      // --- k = 512 cooperatively (j = tid)
      float msh512 = tmaxs[0];
      #pragma unroll
      for (int t2 = 1; t2 < 8; ++t2) msh512 = fmaxf(msh512, tmaxs[t2]);
      float p = bf2f(Ebf[c * S1_ * S1_ + tid * S1_ + 512]) * wexp[tid] *
                exp2f((tmaxs[tid >> 6] - msh512) * L2E);
      #pragma unroll
      for (int o = 1; o < 64; o <<= 1) p += __shfl_xor(p, o);
      if (lane == 0) red[w] = p;
      __syncthreads();                             // barrier C (also end-of-step)
      if (tid == 0) {
        float t2 = ((red[0] + red[1]) + (red[2] + red[3])) +
                   ((red[4] + red[5]) + (red[6] + red[7]));
        areg512 = (t2 > 0.0f) ? (csr[512] + msh512 + log2f(t2) * LN2f) : NEG;
      }
      areg = ar;
      float* orow = obuf + (b * (LP_ + 1) + (s + 1)) * S1_;
      orow[myk] = ar;
      if (tid == 0) orow[512] = areg512;
    } else {
      const ushort_t* erow = ETb + c * S1_ * S1_ + myk;
      { // boundary: k = myk+1 .. tile*64+63
        const float* zp = zl;
        for (int q = lane + 1; q < 64; ++q)
          acc += bf2f(erow[(tile * 64 + q) * S1_]) * exp2f((zp[tile * 64 + q] - msh) * L2E);
      }
      for (int t = tile + 1; t < 8; ++t) {         // wave-uniform bound
        const ushort_t* ep = erow + t * 64 * S1_;
        const float4* wv = (const float4*)(wexp + t * 64);
        float s0 = 0.f, s1 = 0.f, s2 = 0.f, s3 = 0.f;
        #pragma unroll
        for (int q = 0; q < 16; ++q) {
          float4 w4 = wv[q];
          s0 += bf2f(ep[(q * 4 + 0) * S1_]) * w4.x;
          s1 += bf2f(ep[(q * 4 + 1) * S1_]) * w4.y;
          s2 += bf2f(ep[(q * 4 + 2) * S1_]) * w4.z;
          s3 += bf2f(ep[(q * 4 + 3) * S1_]) * w4.w;
        }
        acc += exp2f((tmaxs[t] - msh) * L2E) * ((s0 + s1) + (s2 + s3));
      }
      // k = 512 term
      acc += bf2f(erow[512 * S1_]) * exp2f((tmaxs[8] - msh) * L2E);
      float ar = (acc > 0.0f) ? (msh - csr[myk] + log2f(acc) * LN2f) : NEG;
      areg = ar;
      if (tid == 0) areg512 = NEG;
      float* orow = obuf + (b * (LP_ + 1) + (LP_ - 1 - s)) * S1_;
      orow[myk] = ar;
      if (tid == 0) orow[512] = NEG;
      __syncthreads();                             // end-of-step barrier
    }
  }
}

// ---------------- epilogue ----------------
__global__ void k_out(const float* __restrict__ a_buf, const float* __restrict__ b_buf,
                      const int* __restrict__ ls, float* __restrict__ out) {
  const int TOT = B_ * (LP_ + 1) * S1_;
  int idx = blockIdx.x * 256 + threadIdx.x;
  if (idx >= TOT) return;
  int b = idx / ((LP_ + 1) * S1_);
  float M = a_buf[(b * (LP_ + 1) + LP_) * S1_ + ls[b]];
  out[idx] = a_buf[idx] + b_buf[idx] - M;
}

// ---------------- launcher ----------------
extern "C" void kernel_launch(void* const* d_in, const int* in_sizes, int n_in,
                              void* d_out, int out_size, void* d_ws, size_t ws_size,
                              hipStream_t stream) {
  const float* ss3     = (const float*)d_in[0];
  const float* Q       = (const float*)d_in[1];
  const int*   pattern = (const int*)d_in[2];
  const int*   ls      = (const int*)d_in[3];
  float* out = (float*)d_out;

  float* ws    = (float*)d_ws;
  float* cs    = ws;                                    // B*3*S1      = 49248 f
  float* a_buf = cs + B_ * 3 * S1_;                     // B*(LP+1)*S1 = 279072 f
  float* b_buf = a_buf + B_ * (LP_ + 1) * S1_;          // 279072 f
  ushort_t* Ebf = (ushort_t*)(b_buf + B_ * (LP_ + 1) * S1_);  // 3*S1*S1 us
  ushort_t* ETb = Ebf + 3 * S1_ * S1_ + 1;              // +1 pad (4B align)

  k_cumsum<<<dim3(B_, 3), 512, 0, stream>>>(ss3, cs);
  k_prep  <<<dim3(17, 17, 3), dim3(32, 8), 0, stream>>>(Q, Ebf, ETb);
  k_scan  <<<2 * B_, 512, 0, stream>>>(Ebf, ETb, cs, pattern, ls, a_buf, b_buf);

  const int TOT = B_ * (LP_ + 1) * S1_;
  k_out<<<(TOT + 255) / 256, 256, 0, stream>>>(a_buf, b_buf, ls, out);
}

// Round 3
// 316.414 us; speedup vs baseline: 3.0427x; 1.8977x over previous
//
#include <hip/hip_runtime.h>

#define B_   32
#define L_   512
#define S1_  513
#define LP_  16
#define NEG  (-1.0e9f)
#define NINF (-3.0e38f)
#define L2E  1.4426950408889634f
#define LN2f 0.6931471805599453f

typedef unsigned short ushort_t;

__device__ __forceinline__ float bf2f(ushort_t u) {
  return __uint_as_float(((unsigned int)u) << 16);
}
__device__ __forceinline__ ushort_t f2bf(float f) {
  unsigned int u = __float_as_uint(f);
  unsigned int r = (u + 0x7FFFu + ((u >> 16) & 1u)) >> 16;
  return (ushort_t)r;
}

// full 64x64 subtile weighted sum: sum_j E[j][col] * w[j]
__device__ __forceinline__ float tilesum(const ushort_t* __restrict__ ep,
                                         const float* __restrict__ wv) {
  float s0 = 0.f, s1 = 0.f, s2 = 0.f, s3 = 0.f;
  const float4* w4p = (const float4*)wv;
  #pragma unroll
  for (int q = 0; q < 16; ++q) {
    float4 w4 = w4p[q];
    s0 += bf2f(ep[(q * 4 + 0) * S1_]) * w4.x;
    s1 += bf2f(ep[(q * 4 + 1) * S1_]) * w4.y;
    s2 += bf2f(ep[(q * 4 + 2) * S1_]) * w4.z;
    s3 += bf2f(ep[(q * 4 + 3) * S1_]) * w4.w;
  }
  return (s0 + s1) + (s2 + s3);
}

// ---------------- setup kernels ----------------

__global__ void k_cumsum(const float* __restrict__ ss3, float* __restrict__ cs) {
  int b = blockIdx.x, c = blockIdx.y;
  __shared__ float buf[L_];
  int t = threadIdx.x;
  buf[t] = logf(ss3[(b * 3 + c) * L_ + t]);
  __syncthreads();
  for (int d = 1; d < L_; d <<= 1) {
    float add = (t >= d) ? buf[t - d] : 0.0f;
    __syncthreads();
    buf[t] += add;
    __syncthreads();
  }
  float* out = cs + (b * 3 + c) * S1_;
  if (t == 0) out[0] = 0.0f;
  out[t + 1] = buf[t];
}

__global__ void k_prep(const float* __restrict__ Q, ushort_t* __restrict__ Ebf,
                       ushort_t* __restrict__ ETb) {
  __shared__ float tile[32][33];
  const int c = blockIdx.z;
  const int x = blockIdx.x * 32 + threadIdx.x;
  const float* q = Q + c * S1_ * S1_;
  for (int dy = threadIdx.y; dy < 32; dy += 8) {
    int y = blockIdx.y * 32 + dy;
    if (x < S1_ && y < S1_) {
      float e = expf(q[y * S1_ + x]);
      Ebf[c * S1_ * S1_ + y * S1_ + x] = f2bf(e);
      tile[dy][threadIdx.x] = e;
    }
  }
  __syncthreads();
  const int xT = blockIdx.y * 32 + threadIdx.x;
  for (int dy = threadIdx.y; dy < 32; dy += 8) {
    int yT = blockIdx.x * 32 + dy;
    if (xT < S1_ && yT < S1_)
      ETb[c * S1_ * S1_ + yT * S1_ + xT] = f2bf(tile[threadIdx.x][dy]);
  }
}

// ---------------- main scan kernel ----------------
// 64 blocks x 1024 threads: blockIdx.x = b*2 + dir.
// Waves 0-7 "primary" (phases 1-3 + even j-subtiles + epilogue),
// waves 8-15 "secondary" (odd j-subtiles + boundary diag + bwd k512 term).
__global__ __launch_bounds__(1024) void k_scan(
    const ushort_t* __restrict__ Ebf, const ushort_t* __restrict__ ETb,
    const float* __restrict__ cs, const int* __restrict__ pattern,
    const int* __restrict__ ls,
    float* __restrict__ a_buf, float* __restrict__ b_buf) {
  const int b   = blockIdx.x >> 1;
  const int dir = blockIdx.x & 1;
  const int tid = threadIdx.x;
  const bool pri = tid < 512;
  const int ptid = pri ? tid : tid - 512;
  const int lane = ptid & 63;
  const int w    = ptid >> 6;
  const int tile = (w < 4) ? w : (11 - w);   // SIMD pairing: tiles t and 7-t share a SIMD
  const int myk  = tile * 64 + lane;         // 0..511

  __shared__ float cs3[3 * S1_];
  __shared__ float zl[S1_];
  __shared__ float wexp[512];
  __shared__ float mshl[512];
  __shared__ float psum[512];
  __shared__ float tmaxs[9];                 // [8] = z512 (bwd)
  __shared__ float red[8];
  __shared__ int   pat[LP_];

  for (int i = tid; i < 3 * S1_; i += 1024) cs3[i] = cs[b * 3 * S1_ + i];
  if (tid < LP_) pat[tid] = pattern[tid];
  const int myls = ls[b];

  float* obuf = dir ? b_buf : a_buf;
  float areg = NEG, areg512 = NEG;
  if (pri) {
    const int initk = dir ? myls : 0;
    areg    = (myk == initk) ? 0.0f : NEG;
    areg512 = (dir && myls == 512) ? 0.0f : NEG;
    const int row0 = dir ? LP_ : 0;
    float* orow = obuf + (b * (LP_ + 1) + row0) * S1_;
    orow[myk] = areg;
    if (tid == 0) orow[512] = areg512;
  }
  __syncthreads();

  for (int s = 0; s < LP_; ++s) {
    const int c = pat[dir ? (LP_ - 1 - s) : s];
    const float* csr = cs3 + c * S1_;
    const ushort_t* Ec  = Ebf + c * S1_ * S1_;
    const ushort_t* ETc = ETb + c * S1_ * S1_;

    float pfx = NINF, tmax = 0.f, z = 0.f;
    if (pri) {
      // --- phase 1: z
      const float mycs = csr[myk];
      z = areg + (dir ? mycs : -mycs);
      zl[myk] = z;
      // --- phase 2: per-wave inclusive max scan + tile max
      pfx = z;
      if (!dir) {
        #pragma unroll
        for (int d = 1; d < 64; d <<= 1) {
          float o = __shfl_up(pfx, d);
          if (lane >= d) pfx = fmaxf(pfx, o);
        }
        tmax = __shfl(pfx, 63);
        if (lane == 63) tmaxs[tile] = pfx;
      } else {
        #pragma unroll
        for (int d = 1; d < 64; d <<= 1) {
          float o = __shfl_down(pfx, d);
          if (lane < 64 - d) pfx = fmaxf(pfx, o);
        }
        tmax = __shfl(pfx, 0);
        if (lane == 0) tmaxs[tile] = pfx;
        if (tid == 0) tmaxs[8] = areg512 + csr[512];
      }
    }
    __syncthreads();                               // barrier A

    float msh = 0.f;
    if (pri) {
      // --- phase 3: cross-tile offset -> per-column shift msh; wexp
      if (!dir) {
        float off = NINF;
        for (int t2 = 0; t2 < tile; ++t2) off = fmaxf(off, tmaxs[t2]);
        float p1 = __shfl_up(pfx, 1);
        msh = fmaxf((lane == 0) ? NINF : p1, off);
      } else {
        float off = tmaxs[8];
        for (int t2 = tile + 1; t2 < 8; ++t2) off = fmaxf(off, tmaxs[t2]);
        float p1 = __shfl_down(pfx, 1);
        msh = fmaxf((lane == 63) ? NINF : p1, off);
      }
      mshl[myk] = msh;
      wexp[myk] = exp2f((z - tmax) * L2E);
    }
    __syncthreads();                               // barrier B
    if (!pri) msh = mshl[myk];

    // --- phase 4: triangular weighted sum, j-subtiles split pri/sec
    float acc = 0.0f;
    if (!dir) {
      const ushort_t* ecol = Ec + myk;
      const int t0 = pri ? 0 : 1;
      for (int t = t0; t < tile; t += 2)
        acc += exp2f((tmaxs[t] - msh) * L2E) * tilesum(ecol + t * 64 * S1_, wexp + t * 64);
      if (!pri) {
        // boundary diag subtile: j = tile*64+q, live iff q < lane (fixed trip, predicated)
        const ushort_t* ep = ecol + tile * 64 * S1_;
        const float* zp = zl + tile * 64;
        float b0 = 0.f, b1 = 0.f, b2 = 0.f, b3 = 0.f;
        #pragma unroll 2
        for (int q = 0; q < 64; q += 4) {
          float a0 = (q + 0 < lane) ? (zp[q + 0] - msh) : NEG;
          float a1 = (q + 1 < lane) ? (zp[q + 1] - msh) : NEG;
          float a2 = (q + 2 < lane) ? (zp[q + 2] - msh) : NEG;
          float a3 = (q + 3 < lane) ? (zp[q + 3] - msh) : NEG;
          b0 += bf2f(ep[(q + 0) * S1_]) * exp2f(a0 * L2E);
          b1 += bf2f(ep[(q + 1) * S1_]) * exp2f(a1 * L2E);
          b2 += bf2f(ep[(q + 2) * S1_]) * exp2f(a2 * L2E);
          b3 += bf2f(ep[(q + 3) * S1_]) * exp2f(a3 * L2E);
        }
        acc += (b0 + b1) + (b2 + b3);
        psum[myk] = acc;
      } else {
        // k = 512 contribution (one j per primary thread)
        float msh512 = tmaxs[0];
        #pragma unroll
        for (int t2 = 1; t2 < 8; ++t2) msh512 = fmaxf(msh512, tmaxs[t2]);
        float p = bf2f(Ec[tid * S1_ + 512]) * wexp[tid] *
                  exp2f((tmaxs[tid >> 6] - msh512) * L2E);
        #pragma unroll
        for (int o = 1; o < 64; o <<= 1) p += __shfl_xor(p, o);
        if (lane == 0) red[w] = p;
      }
    } else {
      const ushort_t* erow = ETc + myk;
      const int t0 = tile + (pri ? 1 : 2);
      for (int t = t0; t < 8; t += 2)
        acc += exp2f((tmaxs[t] - msh) * L2E) * tilesum(erow + t * 64 * S1_, wexp + t * 64);
      if (!pri) {
        // boundary diag subtile: k = tile*64+q, live iff q > lane
        const ushort_t* ep = erow + tile * 64 * S1_;
        const float* zp = zl + tile * 64;
        float b0 = 0.f, b1 = 0.f, b2 = 0.f, b3 = 0.f;
        #pragma unroll 2
        for (int q = 0; q < 64; q += 4) {
          float a0 = (q + 0 > lane) ? (zp[q + 0] - msh) : NEG;
          float a1 = (q + 1 > lane) ? (zp[q + 1] - msh) : NEG;
          float a2 = (q + 2 > lane) ? (zp[q + 2] - msh) : NEG;
          float a3 = (q + 3 > lane) ? (zp[q + 3] - msh) : NEG;
          b0 += bf2f(ep[(q + 0) * S1_]) * exp2f(a0 * L2E);
          b1 += bf2f(ep[(q + 1) * S1_]) * exp2f(a1 * L2E);
          b2 += bf2f(ep[(q + 2) * S1_]) * exp2f(a2 * L2E);
          b3 += bf2f(ep[(q + 3) * S1_]) * exp2f(a3 * L2E);
        }
        acc += (b0 + b1) + (b2 + b3);
        acc += bf2f(erow[512 * S1_]) * exp2f((tmaxs[8] - msh) * L2E);   // k = 512 term
        psum[myk] = acc;
      }
    }
    __syncthreads();                               // barrier C

    if (pri) {
      acc += psum[myk];
      if (!dir) {
        float ar = (acc > 0.0f) ? (csr[myk] + msh + log2f(acc) * LN2f) : NEG;
        areg = ar;
        float* orow = obuf + (b * (LP_ + 1) + (s + 1)) * S1_;
        orow[myk] = ar;
        if (tid == 0) {
          float msh512 = tmaxs[0];
          #pragma unroll
          for (int t2 = 1; t2 < 8; ++t2) msh512 = fmaxf(msh512, tmaxs[t2]);
          float t2s = ((red[0] + red[1]) + (red[2] + red[3])) +
                      ((red[4] + red[5]) + (red[6] + red[7]));
          areg512 = (t2s > 0.0f) ? (csr[512] + msh512 + log2f(t2s) * LN2f) : NEG;
          orow[512] = areg512;
        }
      } else {
        float ar = (acc > 0.0f) ? (msh - csr[myk] + log2f(acc) * LN2f) : NEG;
        areg = ar;
        float* orow = obuf + (b * (LP_ + 1) + (LP_ - 1 - s)) * S1_;
        orow[myk] = ar;
        if (tid == 0) { areg512 = NEG; orow[512] = NEG; }
      }
    }
    // no extra barrier needed: secondaries stall at barrier B(s+1) until
    // primaries finish phase 1-3 writes; all secondary LDS reads ended pre-C.
  }
}

// ---------------- epilogue ----------------
__global__ void k_out(const float* __restrict__ a_buf, const float* __restrict__ b_buf,
                      const int* __restrict__ ls, float* __restrict__ out) {
  const int TOT = B_ * (LP_ + 1) * S1_;
  int idx = blockIdx.x * 256 + threadIdx.x;
  if (idx >= TOT) return;
  int b = idx / ((LP_ + 1) * S1_);
  float M = a_buf[(b * (LP_ + 1) + LP_) * S1_ + ls[b]];
  out[idx] = a_buf[idx] + b_buf[idx] - M;
}

// ---------------- launcher ----------------
extern "C" void kernel_launch(void* const* d_in, const int* in_sizes, int n_in,
                              void* d_out, int out_size, void* d_ws, size_t ws_size,
                              hipStream_t stream) {
  const float* ss3     = (const float*)d_in[0];
  const float* Q       = (const float*)d_in[1];
  const int*   pattern = (const int*)d_in[2];
  const int*   ls      = (const int*)d_in[3];
  float* out = (float*)d_out;

  float* ws    = (float*)d_ws;
  float* cs    = ws;                                    // B*3*S1 floats
  float* a_buf = cs + B_ * 3 * S1_;                     // B*(LP+1)*S1
  float* b_buf = a_buf + B_ * (LP_ + 1) * S1_;
  ushort_t* Ebf = (ushort_t*)(b_buf + B_ * (LP_ + 1) * S1_);
  ushort_t* ETb = Ebf + 3 * S1_ * S1_ + 1;              // +1 pad (4B align)

  k_cumsum<<<dim3(B_, 3), 512, 0, stream>>>(ss3, cs);
  k_prep  <<<dim3(17, 17, 3), dim3(32, 8), 0, stream>>>(Q, Ebf, ETb);
  k_scan  <<<2 * B_, 1024, 0, stream>>>(Ebf, ETb, cs, pattern, ls, a_buf, b_buf);

  const int TOT = B_ * (LP_ + 1) * S1_;
  k_out<<<(TOT + 255) / 256, 256, 0, stream>>>(a_buf, b_buf, ls, out);
}